// Round 2
// baseline (11.899 us; speedup 1.0000x reference)
//
#include <hip/hip_runtime.h>
#include <hip/hip_bf16.h>

// ProtienGAT collapses mathematically for these inputs (verified: absmax 0.0):
//
//  Layer-1 GATv2 receives x0 = zeros => xl = g1_bl, xr = g1_br row-constant.
//  sum(alpha) per segment == 1.0 exactly (the max edge has weight exp(0)=1 so
//  the denominator d >= 1; d/(d+1e-16) == 1.0f in f32).
//  => node[j] = g1_bl + g1_b (row-constant).
//  Layer-2 GATv2 likewise: out[j] = (node_c @ g2_Wl + g2_bl) + g2_b.
//  Head: res = log_softmax(out_c @ W_out + b_out), broadcast to all N rows.
//  E, E_idx, S, mask, chain_M, noise, W_e, W_s, all attention params and the
//  argsort/mask_attend machinery are mathematically dead for the output.
//
// Round-2 optimizations (kernel-time, not overhead):
//  - 64 blocks (not 256): each block redundantly reads the 64 KB g2_Wl;
//    4 MB total fetch instead of 16 MB.
//  - Dot products split across threads with multiple accumulators: oc matvec
//    chain 128 -> 16 FMAs; head matvec chain 128 -> 16.
//  - float4 output fill via a 21-entry float4 pattern (lcm(4,21)=84; the
//    float4 at element 4j starts at pattern phase (4j)%84 which is 4-aligned,
//    so store j just uses pat4[j % 21]).

#define PG_H 128
#define PG_V 21

__global__ __launch_bounds__(256) void protien_gat_collapsed(
    const float* __restrict__ g1_bl,   // (H,)
    const float* __restrict__ g1_b,    // (H,)
    const float* __restrict__ g2_Wl,   // (H,H) row-major
    const float* __restrict__ g2_bl,   // (H,)
    const float* __restrict__ g2_b,    // (H,)
    const float* __restrict__ W_out,   // (H,V) row-major
    const float* __restrict__ b_out,   // (V,)
    float* __restrict__ out,           // (N*V,)
    int total)
{
    __shared__ float node_c[PG_H];
    __shared__ float part[256];
    __shared__ float oc[PG_H];
    __shared__ float part2[84];
    __shared__ float res[PG_V];
    __shared__ float4 pat4[PG_V];

    const int t = threadIdx.x;

    // node_c = g1_bl + g1_b   (layer-1 collapsed output)
    if (t < PG_H) node_c[t] = g1_bl[t] + g1_b[t];
    __syncthreads();

    // oc = node_c @ g2_Wl + g2_bl + g2_b
    // 2 threads per output column, 64 k's each, 4 accumulators (chain = 16)
    {
        const int o    = t & (PG_H - 1);
        const int half = t >> 7;           // 0 or 1
        const int k0   = half * 64;
        const float* __restrict__ col = g2_Wl + o;
        float a0 = 0.f, a1 = 0.f, a2 = 0.f, a3 = 0.f;
        #pragma unroll
        for (int k = 0; k < 64; k += 4) {
            a0 += node_c[k0 + k + 0] * col[(k0 + k + 0) * PG_H];
            a1 += node_c[k0 + k + 1] * col[(k0 + k + 1) * PG_H];
            a2 += node_c[k0 + k + 2] * col[(k0 + k + 2) * PG_H];
            a3 += node_c[k0 + k + 3] * col[(k0 + k + 3) * PG_H];
        }
        part[t] = (a0 + a1) + (a2 + a3);
    }
    __syncthreads();
    if (t < PG_H) oc[t] = part[t] + part[t + PG_H] + g2_bl[t] + g2_b[t];
    __syncthreads();

    // res = oc @ W_out + b_out
    // 4 threads per output (84 threads), 32 h's each, 2 accumulators
    if (t < 4 * PG_V) {
        const int o  = t >> 2;
        const int q  = t & 3;
        const int h0 = q * 32;
        float a0 = 0.f, a1 = 0.f;
        #pragma unroll
        for (int h = 0; h < 32; h += 2) {
            a0 += oc[h0 + h]     * W_out[(h0 + h) * PG_V + o];
            a1 += oc[h0 + h + 1] * W_out[(h0 + h + 1) * PG_V + o];
        }
        part2[t] = a0 + a1;
    }
    __syncthreads();
    if (t < PG_V)
        res[t] = part2[4 * t] + part2[4 * t + 1] + part2[4 * t + 2]
               + part2[4 * t + 3] + b_out[t];
    __syncthreads();

    // log_softmax over V=21 (serial on thread 0 — 21 elements, negligible)
    if (t == 0) {
        float m = res[0];
        for (int i = 1; i < PG_V; ++i) m = fmaxf(m, res[i]);
        float s = 0.0f;
        for (int i = 0; i < PG_V; ++i) s += __expf(res[i] - m);
        const float lse = m + __logf(s);
        for (int i = 0; i < PG_V; ++i) res[i] -= lse;
    }
    __syncthreads();

    // build the float4 broadcast pattern: pat4[q] covers elements 4q..4q+3
    if (t < PG_V) {
        const int e = 4 * t;
        pat4[t] = make_float4(res[e % PG_V], res[(e + 1) % PG_V],
                              res[(e + 2) % PG_V], res[(e + 3) % PG_V]);
    }
    __syncthreads();

    // vectorized broadcast fill: out element (4j+r) == res[(4j+r) % 21],
    // and (4j) % 84 is 4-aligned, so the whole float4 is pat4[j % 21].
    float4* __restrict__ out4 = (float4*)out;
    const int total4 = total >> 2;                 // 172032/4 = 43008
    const int stride = gridDim.x * blockDim.x;
    for (int j = blockIdx.x * blockDim.x + t; j < total4; j += stride)
        out4[j] = pat4[j % PG_V];
}

extern "C" void kernel_launch(void* const* d_in, const int* in_sizes, int n_in,
                              void* d_out, int out_size, void* d_ws, size_t ws_size,
                              hipStream_t stream)
{
    // setup_inputs() order:
    //  0 E, 1 E_idx, 2 S, 3 mask, 4 chain_M, 5 noise, 6 W_e, 7 b_e, 8 W_s,
    //  9 g1_Wl, 10 g1_bl, 11 g1_Wr, 12 g1_br, 13 g1_We, 14 g1_att, 15 g1_b,
    // 16 g2_Wl, 17 g2_bl, 18 g2_Wr, 19 g2_br, 20 g2_We, 21 g2_att, 22 g2_b,
    // 23 W_out, 24 b_out
    const float* g1_bl = (const float*)d_in[10];
    const float* g1_b  = (const float*)d_in[15];
    const float* g2_Wl = (const float*)d_in[16];
    const float* g2_bl = (const float*)d_in[17];
    const float* g2_b  = (const float*)d_in[22];
    const float* W_out = (const float*)d_in[23];
    const float* b_out = (const float*)d_in[24];

    float* out = (float*)d_out;

    const int total = out_size;            // 8192 * 21 = 172032
    const int block = 256;
    const int grid  = 64;                  // fewer blocks => less redundant
                                           // g2_Wl fetch (64 KB per block)

    protien_gat_collapsed<<<grid, block, 0, stream>>>(
        g1_bl, g1_b, g2_Wl, g2_bl, g2_b, W_out, b_out, out, total);
}